// Round 1
// baseline (4665.249 us; speedup 1.0000x reference)
//
#include <hip/hip_runtime.h>
#include <math.h>

#define BATCH 2
#define SEQ   2048
#define EMB   2048
#define NH    16
#define HD    128

// ======================= fp32 tiled GEMM =======================
// C[M,N] = A[M,K] * B[K,N], all row-major.
#define TM 64
#define TN 64
#define TK 16

__global__ __launch_bounds__(256) void gemm_f32(
    const float* __restrict__ A, const float* __restrict__ B,
    float* __restrict__ C, int M, int N, int K)
{
    __shared__ float As[TK][TM + 4];   // [k][m]; +4 keeps rows 16B-aligned, banks ok
    __shared__ float Bs[TK][TN + 4];   // [k][n]
    const int tid = threadIdx.x;
    const int tx = tid & 15;       // n / 4
    const int ty = tid >> 4;       // m / 4
    const int row0 = blockIdx.y * TM;
    const int col0 = blockIdx.x * TN;

    float acc[4][4] = {{0.f}};

    for (int k0 = 0; k0 < K; k0 += TK) {
        // A tile 64x16: consecutive tid -> consecutive k (64B segments)
        #pragma unroll
        for (int e = tid; e < TM * TK; e += 256) {
            int c = e & 15, r = e >> 4;
            As[c][r] = A[(size_t)(row0 + r) * K + (k0 + c)];
        }
        // B tile 16x64: consecutive tid -> consecutive n (fully coalesced)
        #pragma unroll
        for (int e = tid; e < TK * TN; e += 256) {
            int c = e & 63, r = e >> 6;
            Bs[r][c] = B[(size_t)(k0 + r) * N + (col0 + c)];
        }
        __syncthreads();
        #pragma unroll
        for (int kk = 0; kk < TK; kk++) {
            float a[4], b[4];
            #pragma unroll
            for (int i = 0; i < 4; i++) a[i] = As[kk][ty * 4 + i];
            #pragma unroll
            for (int j = 0; j < 4; j++) b[j] = Bs[kk][tx * 4 + j];
            #pragma unroll
            for (int i = 0; i < 4; i++)
                #pragma unroll
                for (int j = 0; j < 4; j++)
                    acc[i][j] += a[i] * b[j];
        }
        __syncthreads();
    }
    #pragma unroll
    for (int i = 0; i < 4; i++)
        #pragma unroll
        for (int j = 0; j < 4; j++)
            C[(size_t)(row0 + ty * 4 + i) * N + (col0 + tx * 4 + j)] = acc[i][j];
}

// ======================= RMSNorm over last dim (D=128), in place =======================
__global__ __launch_bounds__(128) void rmsnorm_rows(
    float* __restrict__ buf, const float* __restrict__ scale)
{
    __shared__ float wsum[2];
    const int row = blockIdx.x;
    const int d = threadIdx.x;   // 0..127
    float v = buf[(size_t)row * HD + d];
    float s = v * v;
    #pragma unroll
    for (int off = 1; off < 64; off <<= 1) s += __shfl_xor(s, off, 64);
    if ((d & 63) == 0) wsum[d >> 6] = s;
    __syncthreads();
    float tot = wsum[0] + wsum[1];
    float inv = rsqrtf(tot * (1.0f / HD) + 1e-6f);
    buf[(size_t)row * HD + d] = v * inv * scale[d];
}

// ======================= flash-style attention (fp32) =======================
// grid: (SEQ/64, BATCH*NH), block: 256.
// Q,K already RMS-normed. No 1/sqrt(d) scaling (per reference).
#define TQ  64
#define TKV 64

__global__ __launch_bounds__(256) void attn_f32(
    const float* __restrict__ Q, const float* __restrict__ Kk,
    const float* __restrict__ V, float* __restrict__ O)
{
    __shared__ float Qs[TQ][HD + 4];    // pad 132: float4-aligned rows, 2-way banks (free)
    __shared__ float Ks[TKV][HD + 1];   // pad 129: conflict-free S-compute reads
    __shared__ float Vs[TKV][HD + 4];   // pad 132: float4 PV reads
    __shared__ float St[TKV][TQ + 1];   // scores transposed: St[key][row]
    __shared__ float mrow[TQ], lrow[TQ], arow[TQ];

    const int tid = threadIdx.x;
    const int bh = blockIdx.y;            // 0..31
    const int b = bh / NH, h = bh % NH;
    const int q0 = blockIdx.x * TQ;

    const size_t rstride = (size_t)NH * HD;   // 2048
    const float* Qbase = Q + ((size_t)b * SEQ) * rstride + (size_t)h * HD;
    const float* Kbase = Kk + ((size_t)b * SEQ) * rstride + (size_t)h * HD;
    const float* Vbase = V + ((size_t)b * SEQ) * rstride + (size_t)h * HD;
    float* Obase = O + ((size_t)b * SEQ) * rstride + (size_t)h * HD;

    // ---- load Q tile (float4) ----
    #pragma unroll
    for (int e = tid; e < TQ * (HD / 4); e += 256) {
        int r = e >> 5, c4 = e & 31;
        float4 val = *(const float4*)&Qbase[(size_t)(q0 + r) * rstride + c4 * 4];
        *(float4*)&Qs[r][c4 * 4] = val;
    }
    if (tid < TQ) { mrow[tid] = -1e30f; lrow[tid] = 0.f; }

    // PV / output ownership: row pr = tid&63, cols pc0..pc0+31
    const int pr = tid & 63;
    const int pc0 = (tid >> 6) * 32;
    float acc[32];
    #pragma unroll
    for (int i = 0; i < 32; i++) acc[i] = 0.f;

    // S-compute ownership: rows ty2*4+i, keys tx2*4+j
    const int tx2 = tid & 15;
    const int ty2 = tid >> 4;
    __syncthreads();

    for (int kt = 0; kt < SEQ; kt += TKV) {
        // ---- load K and V tiles ----
        #pragma unroll
        for (int e = tid; e < TKV * (HD / 4); e += 256) {
            int r = e >> 5, c4 = e & 31;
            float4 kv = *(const float4*)&Kbase[(size_t)(kt + r) * rstride + c4 * 4];
            Ks[r][c4 * 4 + 0] = kv.x; Ks[r][c4 * 4 + 1] = kv.y;
            Ks[r][c4 * 4 + 2] = kv.z; Ks[r][c4 * 4 + 3] = kv.w;
            float4 vv = *(const float4*)&Vbase[(size_t)(kt + r) * rstride + c4 * 4];
            *(float4*)&Vs[r][c4 * 4] = vv;
        }
        __syncthreads();

        // ---- S = Q K^T for this tile (4x4 microkernel) ----
        float sacc[4][4] = {{0.f}};
        for (int d0 = 0; d0 < HD; d0++) {
            float a[4], bb[4];
            #pragma unroll
            for (int i = 0; i < 4; i++) a[i] = Qs[ty2 * 4 + i][d0];
            #pragma unroll
            for (int j = 0; j < 4; j++) bb[j] = Ks[tx2 * 4 + j][d0];
            #pragma unroll
            for (int i = 0; i < 4; i++)
                #pragma unroll
                for (int j = 0; j < 4; j++)
                    sacc[i][j] += a[i] * bb[j];
        }
        #pragma unroll
        for (int i = 0; i < 4; i++)
            #pragma unroll
            for (int j = 0; j < 4; j++)
                St[tx2 * 4 + j][ty2 * 4 + i] = sacc[i][j];
        __syncthreads();

        // ---- online softmax update, one thread per row ----
        if (tid < TQ) {
            const int r = tid;
            float m = mrow[r];
            float mn = m;
            for (int j = 0; j < TKV; j++) mn = fmaxf(mn, St[j][r]);
            float al = expf(m - mn);
            float lsum = 0.f;
            for (int j = 0; j < TKV; j++) {
                float p = expf(St[j][r] - mn);
                St[j][r] = p;
                lsum += p;
            }
            mrow[r] = mn;
            lrow[r] = lrow[r] * al + lsum;
            arow[r] = al;
        }
        __syncthreads();

        // ---- acc = acc*alpha + P V ----
        const float al = arow[pr];
        #pragma unroll
        for (int i = 0; i < 32; i++) acc[i] *= al;
        for (int j = 0; j < TKV; j++) {
            float p = St[j][pr];
            const float4* vrow = (const float4*)&Vs[j][pc0];  // wave-uniform (broadcast)
            #pragma unroll
            for (int i4 = 0; i4 < 8; i4++) {
                float4 vv = vrow[i4];
                acc[i4 * 4 + 0] += p * vv.x;
                acc[i4 * 4 + 1] += p * vv.y;
                acc[i4 * 4 + 2] += p * vv.z;
                acc[i4 * 4 + 3] += p * vv.w;
            }
        }
        __syncthreads();
    }

    // ---- write O ----
    const float linv = 1.0f / lrow[pr];
    #pragma unroll
    for (int i = 0; i < 32; i++)
        Obase[(size_t)(q0 + pr) * rstride + pc0 + i] = acc[i] * linv;
}

// ======================= launch =======================
extern "C" void kernel_launch(void* const* d_in, const int* in_sizes, int n_in,
                              void* d_out, int out_size, void* d_ws, size_t ws_size,
                              hipStream_t stream) {
    const float* x  = (const float*)d_in[0];
    const float* wq = (const float*)d_in[1];
    const float* wk = (const float*)d_in[2];
    const float* wv = (const float*)d_in[3];
    const float* wo = (const float*)d_in[4];
    const float* q_scale = (const float*)d_in[5];
    const float* k_scale = (const float*)d_in[6];
    float* out = (float*)d_out;

    const size_t tsz = (size_t)BATCH * SEQ * NH * HD;  // 8388608
    float* q  = (float*)d_ws;
    float* k  = q + tsz;
    float* v  = k + tsz;
    float* ao = v + tsz;   // attention output, pre-projection

    const int M = BATCH * SEQ;  // 4096
    dim3 gblk(256);
    dim3 ggrid(EMB / TN, M / TM);  // (32, 64)

    gemm_f32<<<ggrid, gblk, 0, stream>>>(x, wq, q, M, NH * HD, EMB);
    gemm_f32<<<ggrid, gblk, 0, stream>>>(x, wk, k, M, NH * HD, EMB);
    gemm_f32<<<ggrid, gblk, 0, stream>>>(x, wv, v, M, NH * HD, EMB);

    rmsnorm_rows<<<M * NH, 128, 0, stream>>>(q, q_scale);
    rmsnorm_rows<<<M * NH, 128, 0, stream>>>(k, k_scale);

    dim3 agrid(SEQ / TQ, BATCH * NH);  // (32, 32)
    attn_f32<<<agrid, 256, 0, stream>>>(q, k, v, ao);

    gemm_f32<<<ggrid, gblk, 0, stream>>>(ao, wo, out, M, EMB, NH * HD);
}

// Round 2
// 2289.826 us; speedup vs baseline: 2.0374x; 2.0374x over previous
//
#include <hip/hip_runtime.h>
#include <hip/hip_bf16.h>
#include <math.h>

#define BATCH 2
#define SEQ   2048
#define EMB   2048
#define NH    16
#define HD    128

typedef __attribute__((ext_vector_type(8))) short short8;
typedef __attribute__((ext_vector_type(4))) float floatx4;

__device__ inline void async_load16(const void* g, void* l) {
    __builtin_amdgcn_global_load_lds(
        (const __attribute__((address_space(1))) unsigned int*)g,
        (__attribute__((address_space(3))) unsigned int*)l, 16, 0, 0);
}

__device__ inline unsigned short f32_to_bf16_bits(float f) {
    __hip_bfloat16 b = __float2bfloat16(f);
    return *(unsigned short*)&b;
}

// ======================= bf16 MFMA GEMM (m97 structure) =======================
// C[M,N] fp32 = A[M,K] bf16 row-major  ×  Bt[N,K] bf16 row-major (B transposed)
// 128x128 tile, BK=32, 256 threads = 4 waves in 2x2 quadrants of 64x64,
// each wave: 4x4 grid of 16x16x32 MFMA frags.
#define GT 128
#define GK 32

__global__ __launch_bounds__(256) void gemm_bf16(
    const __hip_bfloat16* __restrict__ A,
    const __hip_bfloat16* __restrict__ Bt,
    float* __restrict__ C, int M, int N, int K)
{
    // no padding: global_load_lds requires contiguous lane-order layout
    __shared__ unsigned short As[GT * GK];  // [m][k], row stride 32 (64 B)
    __shared__ unsigned short Bs[GT * GK];  // [n][k]

    const int tid  = threadIdx.x;
    const int w    = tid >> 6;        // wave 0..3
    const int lane = tid & 63;
    const int wr   = w >> 1, wc = w & 1;
    const int row0 = blockIdx.y * GT;
    const int col0 = blockIdx.x * GT;

    floatx4 acc[4][4];
    #pragma unroll
    for (int i = 0; i < 4; i++)
        #pragma unroll
        for (int j = 0; j < 4; j++)
            acc[i][j] = (floatx4){0.f, 0.f, 0.f, 0.f};

    // staging: chunk c (0..7) = 16 rows of 32 bf16 = 1024 B; lane covers
    // row c*16 + lane/4, k-elems (lane&3)*8 .. +7  (16 B per lane)
    const int srow  = lane >> 2;
    const int skoff = (lane & 3) * 8;
    const int fm = lane & 15;
    const int fk = (lane >> 4) * 8;   // quad*8

    for (int k0 = 0; k0 < K; k0 += GK) {
        #pragma unroll
        for (int t = 0; t < 2; t++) {
            const int c = w * 2 + t;
            const __hip_bfloat16* ga = A  + (size_t)(row0 + c * 16 + srow) * K + k0 + skoff;
            async_load16(ga, (char*)As + c * 1024);
            const __hip_bfloat16* gb = Bt + (size_t)(col0 + c * 16 + srow) * K + k0 + skoff;
            async_load16(gb, (char*)Bs + c * 1024);
        }
        __syncthreads();   // drains vmcnt -> staging visible

        short8 af[4], bf[4];
        #pragma unroll
        for (int i = 0; i < 4; i++) {
            af[i] = *(const short8*)&As[(wr * 64 + i * 16 + fm) * GK + fk];
            bf[i] = *(const short8*)&Bs[(wc * 64 + i * 16 + fm) * GK + fk];
        }
        #pragma unroll
        for (int i = 0; i < 4; i++)
            #pragma unroll
            for (int j = 0; j < 4; j++)
                acc[i][j] = __builtin_amdgcn_mfma_f32_16x16x32_bf16(af[i], bf[j], acc[i][j], 0, 0, 0);
        __syncthreads();   // protect LDS before next stage
    }

    // epilogue: C/D layout col=lane&15, row=quad*4+reg  [verified m89/m91]
    const int quad = lane >> 4;
    #pragma unroll
    for (int i = 0; i < 4; i++)
        #pragma unroll
        for (int j = 0; j < 4; j++) {
            const size_t base = (size_t)(row0 + wr * 64 + i * 16 + quad * 4) * N
                              + col0 + wc * 64 + j * 16 + fm;
            #pragma unroll
            for (int r = 0; r < 4; r++)
                C[base + (size_t)r * N] = acc[i][j][r];
        }
}

// ======================= cast fp32 -> bf16 (4 elems/thread) =======================
__global__ __launch_bounds__(256) void cast_f32_bf16(
    const float* __restrict__ in, __hip_bfloat16* __restrict__ o, int n)
{
    int i = (blockIdx.x * 256 + threadIdx.x) * 4;
    if (i >= n) return;
    float4 v = *(const float4*)&in[i];
    ushort4 u;
    u.x = f32_to_bf16_bits(v.x);
    u.y = f32_to_bf16_bits(v.y);
    u.z = f32_to_bf16_bits(v.z);
    u.w = f32_to_bf16_bits(v.w);
    *(ushort4*)&o[i] = u;
}

// ======================= transpose + cast: W[K,N] fp32 -> Wt[N,K] bf16 =======================
__global__ __launch_bounds__(256) void transpose_cast(
    const float* __restrict__ W, __hip_bfloat16* __restrict__ Wt, int K, int N)
{
    __shared__ float tile[32][33];
    const int k0 = blockIdx.y * 32, n0 = blockIdx.x * 32;
    const int tx = threadIdx.x, ty = threadIdx.y;  // (32,8)
    #pragma unroll
    for (int i = 0; i < 4; i++)
        tile[ty + i * 8][tx] = W[(size_t)(k0 + ty + i * 8) * N + n0 + tx];
    __syncthreads();
    #pragma unroll
    for (int i = 0; i < 4; i++) {
        float v = tile[tx][ty + i * 8];
        Wt[(size_t)(n0 + ty + i * 8) * K + k0 + tx] = __float2bfloat16(v);
    }
}

// ======================= RMSNorm over last dim (D=128), in place =======================
__global__ __launch_bounds__(128) void rmsnorm_rows(
    float* __restrict__ buf, const float* __restrict__ scale)
{
    __shared__ float wsum[2];
    const int row = blockIdx.x;
    const int d = threadIdx.x;   // 0..127
    float v = buf[(size_t)row * HD + d];
    float s = v * v;
    #pragma unroll
    for (int off = 1; off < 64; off <<= 1) s += __shfl_xor(s, off, 64);
    if ((d & 63) == 0) wsum[d >> 6] = s;
    __syncthreads();
    float tot = wsum[0] + wsum[1];
    float inv = rsqrtf(tot * (1.0f / HD) + 1e-6f);
    buf[(size_t)row * HD + d] = v * inv * scale[d];
}

// ======================= flash-style attention (fp32) =======================
#define TQ  64
#define TKV 64

__global__ __launch_bounds__(256) void attn_f32(
    const float* __restrict__ Q, const float* __restrict__ Kk,
    const float* __restrict__ V, float* __restrict__ O)
{
    __shared__ float Qs[TQ][HD + 4];
    __shared__ float Ks[TKV][HD + 1];
    __shared__ float Vs[TKV][HD + 4];
    __shared__ float St[TKV][TQ + 1];
    __shared__ float mrow[TQ], lrow[TQ], arow[TQ];

    const int tid = threadIdx.x;
    const int bh = blockIdx.y;
    const int b = bh / NH, h = bh % NH;
    const int q0 = blockIdx.x * TQ;

    const size_t rstride = (size_t)NH * HD;
    const float* Qbase = Q + ((size_t)b * SEQ) * rstride + (size_t)h * HD;
    const float* Kbase = Kk + ((size_t)b * SEQ) * rstride + (size_t)h * HD;
    const float* Vbase = V + ((size_t)b * SEQ) * rstride + (size_t)h * HD;
    float* Obase = O + ((size_t)b * SEQ) * rstride + (size_t)h * HD;

    #pragma unroll
    for (int e = tid; e < TQ * (HD / 4); e += 256) {
        int r = e >> 5, c4 = e & 31;
        float4 val = *(const float4*)&Qbase[(size_t)(q0 + r) * rstride + c4 * 4];
        *(float4*)&Qs[r][c4 * 4] = val;
    }
    if (tid < TQ) { mrow[tid] = -1e30f; lrow[tid] = 0.f; }

    const int pr = tid & 63;
    const int pc0 = (tid >> 6) * 32;
    float acc[32];
    #pragma unroll
    for (int i = 0; i < 32; i++) acc[i] = 0.f;

    const int tx2 = tid & 15;
    const int ty2 = tid >> 4;
    __syncthreads();

    for (int kt = 0; kt < SEQ; kt += TKV) {
        #pragma unroll
        for (int e = tid; e < TKV * (HD / 4); e += 256) {
            int r = e >> 5, c4 = e & 31;
            float4 kv = *(const float4*)&Kbase[(size_t)(kt + r) * rstride + c4 * 4];
            Ks[r][c4 * 4 + 0] = kv.x; Ks[r][c4 * 4 + 1] = kv.y;
            Ks[r][c4 * 4 + 2] = kv.z; Ks[r][c4 * 4 + 3] = kv.w;
            float4 vv = *(const float4*)&Vbase[(size_t)(kt + r) * rstride + c4 * 4];
            *(float4*)&Vs[r][c4 * 4] = vv;
        }
        __syncthreads();

        float sacc[4][4] = {{0.f}};
        for (int d0 = 0; d0 < HD; d0++) {
            float a[4], bb[4];
            #pragma unroll
            for (int i = 0; i < 4; i++) a[i] = Qs[ty2 * 4 + i][d0];
            #pragma unroll
            for (int j = 0; j < 4; j++) bb[j] = Ks[tx2 * 4 + j][d0];
            #pragma unroll
            for (int i = 0; i < 4; i++)
                #pragma unroll
                for (int j = 0; j < 4; j++)
                    sacc[i][j] += a[i] * bb[j];
        }
        #pragma unroll
        for (int i = 0; i < 4; i++)
            #pragma unroll
            for (int j = 0; j < 4; j++)
                St[tx2 * 4 + j][ty2 * 4 + i] = sacc[i][j];
        __syncthreads();

        if (tid < TQ) {
            const int r = tid;
            float m = mrow[r];
            float mn = m;
            for (int j = 0; j < TKV; j++) mn = fmaxf(mn, St[j][r]);
            float al = expf(m - mn);
            float lsum = 0.f;
            for (int j = 0; j < TKV; j++) {
                float p = expf(St[j][r] - mn);
                St[j][r] = p;
                lsum += p;
            }
            mrow[r] = mn;
            lrow[r] = lrow[r] * al + lsum;
            arow[r] = al;
        }
        __syncthreads();

        const float al = arow[pr];
        #pragma unroll
        for (int i = 0; i < 32; i++) acc[i] *= al;
        for (int j = 0; j < TKV; j++) {
            float p = St[j][pr];
            const float4* vrow = (const float4*)&Vs[j][pc0];
            #pragma unroll
            for (int i4 = 0; i4 < 8; i4++) {
                float4 vv = vrow[i4];
                acc[i4 * 4 + 0] += p * vv.x;
                acc[i4 * 4 + 1] += p * vv.y;
                acc[i4 * 4 + 2] += p * vv.z;
                acc[i4 * 4 + 3] += p * vv.w;
            }
        }
        __syncthreads();
    }

    const float linv = 1.0f / lrow[pr];
    #pragma unroll
    for (int i = 0; i < 32; i++)
        Obase[(size_t)(q0 + pr) * rstride + pc0 + i] = acc[i] * linv;
}

// ======================= launch =======================
extern "C" void kernel_launch(void* const* d_in, const int* in_sizes, int n_in,
                              void* d_out, int out_size, void* d_ws, size_t ws_size,
                              hipStream_t stream) {
    const float* x  = (const float*)d_in[0];
    const float* wq = (const float*)d_in[1];
    const float* wk = (const float*)d_in[2];
    const float* wv = (const float*)d_in[3];
    const float* wo = (const float*)d_in[4];
    const float* q_scale = (const float*)d_in[5];
    const float* k_scale = (const float*)d_in[6];
    float* out = (float*)d_out;

    const size_t T = (size_t)BATCH * SEQ * NH * HD;   // 8388608
    const size_t W = (size_t)EMB * NH * HD;           // 4194304

    float* q  = (float*)d_ws;
    float* k  = q + T;
    float* v  = k + T;
    float* ao = v + T;
    __hip_bfloat16* xb  = (__hip_bfloat16*)(ao + T);
    __hip_bfloat16* aob = xb + T;
    __hip_bfloat16* wqT = aob + T;
    __hip_bfloat16* wkT = wqT + W;
    __hip_bfloat16* wvT = wkT + W;
    __hip_bfloat16* woT = wvT + W;

    const int M = BATCH * SEQ;   // 4096
    const int N = NH * HD;       // 2048
    const int K = EMB;           // 2048

    // casts / transposes
    cast_f32_bf16<<<(int)(T / 4 + 255) / 256, 256, 0, stream>>>(x, xb, (int)T);
    dim3 tgrid(N / 32, K / 32), tblk(32, 8);
    transpose_cast<<<tgrid, tblk, 0, stream>>>(wq, wqT, K, N);
    transpose_cast<<<tgrid, tblk, 0, stream>>>(wk, wkT, K, N);
    transpose_cast<<<tgrid, tblk, 0, stream>>>(wv, wvT, K, N);
    transpose_cast<<<dim3(EMB / 32, (NH * HD) / 32), tblk, 0, stream>>>(wo, woT, NH * HD, EMB);

    // projections
    dim3 ggrid(N / GT, M / GT);   // (16, 32)
    gemm_bf16<<<ggrid, 256, 0, stream>>>(xb, wqT, q, M, N, K);
    gemm_bf16<<<ggrid, 256, 0, stream>>>(xb, wkT, k, M, N, K);
    gemm_bf16<<<ggrid, 256, 0, stream>>>(xb, wvT, v, M, N, K);

    rmsnorm_rows<<<M * NH, 128, 0, stream>>>(q, q_scale);
    rmsnorm_rows<<<M * NH, 128, 0, stream>>>(k, k_scale);

    dim3 agrid(SEQ / TQ, BATCH * NH);
    attn_f32<<<agrid, 256, 0, stream>>>(q, k, v, ao);

    cast_f32_bf16<<<(int)(T / 4 + 255) / 256, 256, 0, stream>>>(ao, aob, (int)T);
    gemm_bf16<<<dim3(EMB / GT, M / GT), 256, 0, stream>>>(aob, woT, out, M, EMB, NH * HD);
}

// Round 3
// 801.079 us; speedup vs baseline: 5.8237x; 2.8584x over previous
//
#include <hip/hip_runtime.h>
#include <hip/hip_bf16.h>
#include <math.h>

#define BATCH 2
#define SEQ   2048
#define EMB   2048
#define NH    16
#define HD    128

typedef __attribute__((ext_vector_type(8))) short short8;
typedef __attribute__((ext_vector_type(4))) float floatx4;

__device__ inline void async_load16(const void* g, void* l) {
    __builtin_amdgcn_global_load_lds(
        (const __attribute__((address_space(1))) unsigned int*)g,
        (__attribute__((address_space(3))) unsigned int*)l, 16, 0, 0);
}

__device__ inline unsigned short bf16_bits(float f) {
    __hip_bfloat16 b = __float2bfloat16(f);
    return *(unsigned short*)&b;
}
__device__ inline void split_bf16(float f, unsigned short& h, unsigned short& l) {
    __hip_bfloat16 hb = __float2bfloat16(f);
    h = *(unsigned short*)&hb;
    float r = f - __bfloat162float(hb);
    __hip_bfloat16 lb = __float2bfloat16(r);
    l = *(unsigned short*)&lb;
}

// ======================= plain bf16 MFMA GEMM (m97 structure) =======================
// C[M,N] fp32 = A[M,K] bf16 x Bt[N,K] bf16
#define GT 128
#define GK 32

__global__ __launch_bounds__(256) void gemm_bf16(
    const unsigned short* __restrict__ A,
    const unsigned short* __restrict__ Bt,
    float* __restrict__ C, int M, int N, int K)
{
    __shared__ unsigned short As[GT * GK];
    __shared__ unsigned short Bs[GT * GK];

    const int tid  = threadIdx.x;
    const int w    = tid >> 6;
    const int lane = tid & 63;
    const int wr   = w >> 1, wc = w & 1;
    const int row0 = blockIdx.y * GT;
    const int col0 = blockIdx.x * GT;

    floatx4 acc[4][4];
    #pragma unroll
    for (int i = 0; i < 4; i++)
        #pragma unroll
        for (int j = 0; j < 4; j++)
            acc[i][j] = (floatx4){0.f, 0.f, 0.f, 0.f};

    const int srow  = lane >> 2;
    const int skoff = (lane & 3) * 8;
    const int fm = lane & 15;
    const int fk = (lane >> 4) * 8;

    for (int k0 = 0; k0 < K; k0 += GK) {
        #pragma unroll
        for (int t = 0; t < 2; t++) {
            const int c = w * 2 + t;
            async_load16(A  + (size_t)(row0 + c * 16 + srow) * K + k0 + skoff, (char*)As + c * 1024);
            async_load16(Bt + (size_t)(col0 + c * 16 + srow) * K + k0 + skoff, (char*)Bs + c * 1024);
        }
        __syncthreads();

        short8 af[4], bf[4];
        #pragma unroll
        for (int i = 0; i < 4; i++) {
            af[i] = *(const short8*)&As[(wr * 64 + i * 16 + fm) * GK + fk];
            bf[i] = *(const short8*)&Bs[(wc * 64 + i * 16 + fm) * GK + fk];
        }
        #pragma unroll
        for (int i = 0; i < 4; i++)
            #pragma unroll
            for (int j = 0; j < 4; j++)
                acc[i][j] = __builtin_amdgcn_mfma_f32_16x16x32_bf16(af[i], bf[j], acc[i][j], 0, 0, 0);
        __syncthreads();
    }

    const int quad = lane >> 4;
    #pragma unroll
    for (int i = 0; i < 4; i++)
        #pragma unroll
        for (int j = 0; j < 4; j++) {
            const size_t base = (size_t)(row0 + wr * 64 + i * 16 + quad * 4) * N
                              + col0 + wc * 64 + j * 16 + fm;
            #pragma unroll
            for (int r = 0; r < 4; r++)
                C[base + (size_t)r * N] = acc[i][j][r];
        }
}

// ======================= split (hi/lo) bf16 MFMA GEMM: ~fp32 accuracy =======================
__global__ __launch_bounds__(256) void gemm_bf16_split(
    const unsigned short* __restrict__ Ah, const unsigned short* __restrict__ Al,
    const unsigned short* __restrict__ Bh, const unsigned short* __restrict__ Bl,
    float* __restrict__ C, int M, int N, int K)
{
    __shared__ unsigned short AsH[GT * GK], AsL[GT * GK];
    __shared__ unsigned short BsH[GT * GK], BsL[GT * GK];

    const int tid  = threadIdx.x;
    const int w    = tid >> 6;
    const int lane = tid & 63;
    const int wr   = w >> 1, wc = w & 1;
    const int row0 = blockIdx.y * GT;
    const int col0 = blockIdx.x * GT;

    floatx4 acc[4][4];
    #pragma unroll
    for (int i = 0; i < 4; i++)
        #pragma unroll
        for (int j = 0; j < 4; j++)
            acc[i][j] = (floatx4){0.f, 0.f, 0.f, 0.f};

    const int srow  = lane >> 2;
    const int skoff = (lane & 3) * 8;
    const int fm = lane & 15;
    const int fk = (lane >> 4) * 8;

    for (int k0 = 0; k0 < K; k0 += GK) {
        #pragma unroll
        for (int t = 0; t < 2; t++) {
            const int c = w * 2 + t;
            const size_t ao = (size_t)(row0 + c * 16 + srow) * K + k0 + skoff;
            const size_t bo = (size_t)(col0 + c * 16 + srow) * K + k0 + skoff;
            async_load16(Ah + ao, (char*)AsH + c * 1024);
            async_load16(Al + ao, (char*)AsL + c * 1024);
            async_load16(Bh + bo, (char*)BsH + c * 1024);
            async_load16(Bl + bo, (char*)BsL + c * 1024);
        }
        __syncthreads();

        short8 afh[4], afl[4], bfh[4], bfl[4];
        #pragma unroll
        for (int i = 0; i < 4; i++) {
            const int arow = (wr * 64 + i * 16 + fm) * GK + fk;
            const int brow = (wc * 64 + i * 16 + fm) * GK + fk;
            afh[i] = *(const short8*)&AsH[arow];
            afl[i] = *(const short8*)&AsL[arow];
            bfh[i] = *(const short8*)&BsH[brow];
            bfl[i] = *(const short8*)&BsL[brow];
        }
        #pragma unroll
        for (int i = 0; i < 4; i++)
            #pragma unroll
            for (int j = 0; j < 4; j++) {
                acc[i][j] = __builtin_amdgcn_mfma_f32_16x16x32_bf16(afh[i], bfh[j], acc[i][j], 0, 0, 0);
                acc[i][j] = __builtin_amdgcn_mfma_f32_16x16x32_bf16(afh[i], bfl[j], acc[i][j], 0, 0, 0);
                acc[i][j] = __builtin_amdgcn_mfma_f32_16x16x32_bf16(afl[i], bfh[j], acc[i][j], 0, 0, 0);
            }
        __syncthreads();
    }

    const int quad = lane >> 4;
    #pragma unroll
    for (int i = 0; i < 4; i++)
        #pragma unroll
        for (int j = 0; j < 4; j++) {
            const size_t base = (size_t)(row0 + wr * 64 + i * 16 + quad * 4) * N
                              + col0 + wc * 64 + j * 16 + fm;
            #pragma unroll
            for (int r = 0; r < 4; r++)
                C[base + (size_t)r * N] = acc[i][j][r];
        }
}

// ======================= casts =======================
__global__ __launch_bounds__(256) void cast_split_f32(
    const float* __restrict__ in, unsigned short* __restrict__ hi,
    unsigned short* __restrict__ lo, int n)
{
    int i = (blockIdx.x * 256 + threadIdx.x) * 4;
    if (i >= n) return;
    float4 v = *(const float4*)&in[i];
    ushort4 h, l;
    split_bf16(v.x, h.x, l.x);
    split_bf16(v.y, h.y, l.y);
    split_bf16(v.z, h.z, l.z);
    split_bf16(v.w, h.w, l.w);
    *(ushort4*)&hi[i] = h;
    *(ushort4*)&lo[i] = l;
}

__global__ __launch_bounds__(256) void transpose_cast(
    const float* __restrict__ W, unsigned short* __restrict__ Wt, int K, int N)
{
    __shared__ float tile[32][33];
    const int k0 = blockIdx.y * 32, n0 = blockIdx.x * 32;
    const int tx = threadIdx.x, ty = threadIdx.y;
    #pragma unroll
    for (int i = 0; i < 4; i++)
        tile[ty + i * 8][tx] = W[(size_t)(k0 + ty + i * 8) * N + n0 + tx];
    __syncthreads();
    #pragma unroll
    for (int i = 0; i < 4; i++)
        Wt[(size_t)(n0 + ty + i * 8) * K + k0 + tx] = bf16_bits(tile[tx][ty + i * 8]);
}

__global__ __launch_bounds__(256) void transpose_cast_split(
    const float* __restrict__ W, unsigned short* __restrict__ WtH,
    unsigned short* __restrict__ WtL, int K, int N)
{
    __shared__ float tile[32][33];
    const int k0 = blockIdx.y * 32, n0 = blockIdx.x * 32;
    const int tx = threadIdx.x, ty = threadIdx.y;
    #pragma unroll
    for (int i = 0; i < 4; i++)
        tile[ty + i * 8][tx] = W[(size_t)(k0 + ty + i * 8) * N + n0 + tx];
    __syncthreads();
    #pragma unroll
    for (int i = 0; i < 4; i++) {
        unsigned short h, l;
        split_bf16(tile[tx][ty + i * 8], h, l);
        size_t idx = (size_t)(n0 + ty + i * 8) * K + k0 + tx;
        WtH[idx] = h;
        WtL[idx] = l;
    }
}

// ======================= RMSNorm (D=128), in place =======================
__global__ __launch_bounds__(128) void rmsnorm_rows(
    float* __restrict__ buf, const float* __restrict__ scale)
{
    __shared__ float wsum[2];
    const int row = blockIdx.x;
    const int d = threadIdx.x;
    float v = buf[(size_t)row * HD + d];
    float s = v * v;
    #pragma unroll
    for (int off = 1; off < 64; off <<= 1) s += __shfl_xor(s, off, 64);
    if ((d & 63) == 0) wsum[d >> 6] = s;
    __syncthreads();
    float inv = rsqrtf((wsum[0] + wsum[1]) * (1.0f / HD) + 1e-6f);
    buf[(size_t)row * HD + d] = v * inv * scale[d];
}

// ======================= MFMA flash attention =======================
// grid (SEQ/128, BATCH*NH), 256 threads = 4 waves; wave w owns q-rows w*32..w*32+31.
// Q in registers (hi/lo split); K staged hi+lo; 3-term QK^T -> ~fp32 scores;
// online softmax in registers; P->bf16 via LDS (aliases Ks_lo); PV in MFMA.
#define ATQ 128
#define ATK 64
#define KS_STRIDE 136   // 128 + 8 shorts: 272 B rows (16B-aligned, banks spread)
#define PS_STRIDE 72    // 64 + 8
#define VS_STRIDE 72

__global__ __launch_bounds__(256, 2) void attn_mfma(
    const float* __restrict__ Q, const float* __restrict__ Kk,
    const float* __restrict__ V, __hip_bfloat16* __restrict__ AO)
{
    __shared__ unsigned short KsH[ATK * KS_STRIDE];   // 17408 B
    __shared__ unsigned short KLP[ATQ * PS_STRIDE];   // 18432 B: Ks_lo | P (barrier-separated)
    __shared__ unsigned short VsT[HD * VS_STRIDE];    // 18432 B  V^T[d][key]

    const int tid  = threadIdx.x;
    const int w    = tid >> 6;
    const int lane = tid & 63;
    const int quad = lane >> 4;
    const int fm   = lane & 15;
    const int bh = blockIdx.y;
    const int b = bh >> 4, h = bh & 15;
    const int q0 = blockIdx.x * ATQ;

    const size_t rstr = (size_t)NH * HD;                     // 2048
    const size_t base = ((size_t)b * SEQ * NH + h) * HD;     // elem(s,d) = base + s*rstr + d

    // ---- load Q fragments into registers, hi/lo split ----
    short8 qh[2][4], ql[2][4];
    #pragma unroll
    for (int i = 0; i < 2; i++) {
        const int row = q0 + w * 32 + i * 16 + fm;
        #pragma unroll
        for (int kc = 0; kc < 4; kc++) {
            const int d = kc * 32 + quad * 8;
            float4 v0 = *(const float4*)&Q[base + (size_t)row * rstr + d];
            float4 v1 = *(const float4*)&Q[base + (size_t)row * rstr + d + 4];
            float f[8] = {v0.x, v0.y, v0.z, v0.w, v1.x, v1.y, v1.z, v1.w};
            #pragma unroll
            for (int e = 0; e < 8; e++) {
                unsigned short hh, ll;
                split_bf16(f[e], hh, ll);
                qh[i][kc][e] = (short)hh;
                ql[i][kc][e] = (short)ll;
            }
        }
    }

    floatx4 oacc[2][8];
    #pragma unroll
    for (int i = 0; i < 2; i++)
        #pragma unroll
        for (int df = 0; df < 8; df++)
            oacc[i][df] = (floatx4){0.f, 0.f, 0.f, 0.f};
    float m_[2][4], l_[2][4];
    #pragma unroll
    for (int i = 0; i < 2; i++)
        #pragma unroll
        for (int r = 0; r < 4; r++) { m_[i][r] = -1e30f; l_[i][r] = 0.f; }

    const int skey = tid >> 2;       // staging: key 0..63
    const int sdg  = tid & 3;

    for (int kt = 0; kt < SEQ; kt += ATK) {
        __syncthreads();   // prev tile's Ps/Vs reads done before restaging

        // ---- stage K (hi+lo) and V^T (bf16) ----
        #pragma unroll
        for (int i2 = 0; i2 < 8; i2++) {
            const int d = sdg * 4 + i2 * 16;
            const size_t goff = base + (size_t)(kt + skey) * rstr + d;
            float4 kv = *(const float4*)&Kk[goff];
            float kf[4] = {kv.x, kv.y, kv.z, kv.w};
            ushort4 h4, l4;
            split_bf16(kf[0], h4.x, l4.x);
            split_bf16(kf[1], h4.y, l4.y);
            split_bf16(kf[2], h4.z, l4.z);
            split_bf16(kf[3], h4.w, l4.w);
            *(ushort4*)&KsH[skey * KS_STRIDE + d] = h4;
            *(ushort4*)&KLP[skey * KS_STRIDE + d] = l4;
            float4 vv = *(const float4*)&V[goff];
            VsT[(d + 0) * VS_STRIDE + skey] = bf16_bits(vv.x);
            VsT[(d + 1) * VS_STRIDE + skey] = bf16_bits(vv.y);
            VsT[(d + 2) * VS_STRIDE + skey] = bf16_bits(vv.z);
            VsT[(d + 3) * VS_STRIDE + skey] = bf16_bits(vv.w);
        }
        __syncthreads();

        // ---- S = Q K^T (3-term hi/lo) ----
        floatx4 sacc[2][4];
        #pragma unroll
        for (int i = 0; i < 2; i++)
            #pragma unroll
            for (int jf = 0; jf < 4; jf++)
                sacc[i][jf] = (floatx4){0.f, 0.f, 0.f, 0.f};
        #pragma unroll
        for (int kc = 0; kc < 4; kc++)
            #pragma unroll
            for (int jf = 0; jf < 4; jf++) {
                const int koff = (jf * 16 + fm) * KS_STRIDE + kc * 32 + quad * 8;
                short8 kh = *(const short8*)&KsH[koff];
                short8 kl = *(const short8*)&KLP[koff];
                #pragma unroll
                for (int i = 0; i < 2; i++) {
                    sacc[i][jf] = __builtin_amdgcn_mfma_f32_16x16x32_bf16(qh[i][kc], kh, sacc[i][jf], 0, 0, 0);
                    sacc[i][jf] = __builtin_amdgcn_mfma_f32_16x16x32_bf16(qh[i][kc], kl, sacc[i][jf], 0, 0, 0);
                    sacc[i][jf] = __builtin_amdgcn_mfma_f32_16x16x32_bf16(ql[i][kc], kh, sacc[i][jf], 0, 0, 0);
                }
            }

        // ---- online softmax (registers; rows live on (quad, reg)) ----
        float alpha_[2][4];
        #pragma unroll
        for (int i = 0; i < 2; i++)
            #pragma unroll
            for (int r = 0; r < 4; r++) {
                float mx = fmaxf(fmaxf(sacc[i][0][r], sacc[i][1][r]),
                                 fmaxf(sacc[i][2][r], sacc[i][3][r]));
                mx = fmaxf(mx, __shfl_xor(mx, 1));
                mx = fmaxf(mx, __shfl_xor(mx, 2));
                mx = fmaxf(mx, __shfl_xor(mx, 4));
                mx = fmaxf(mx, __shfl_xor(mx, 8));
                const float mold = m_[i][r];
                const float mnew = fmaxf(mold, mx);
                const float al = __expf(mold - mnew);
                m_[i][r] = mnew;
                alpha_[i][r] = al;
                float rs = 0.f;
                #pragma unroll
                for (int jf = 0; jf < 4; jf++) {
                    float p = __expf(sacc[i][jf][r] - mnew);
                    sacc[i][jf][r] = p;
                    rs += p;
                }
                rs += __shfl_xor(rs, 1);
                rs += __shfl_xor(rs, 2);
                rs += __shfl_xor(rs, 4);
                rs += __shfl_xor(rs, 8);
                l_[i][r] = l_[i][r] * al + rs;
            }
        #pragma unroll
        for (int i = 0; i < 2; i++)
            #pragma unroll
            for (int df = 0; df < 8; df++)
                #pragma unroll
                for (int r = 0; r < 4; r++)
                    oacc[i][df][r] *= alpha_[i][r];

        __syncthreads();   // all waves done reading Ks_lo before P overwrites it

        // ---- P -> bf16 into KLP (own rows only) ----
        #pragma unroll
        for (int i = 0; i < 2; i++)
            #pragma unroll
            for (int jf = 0; jf < 4; jf++)
                #pragma unroll
                for (int r = 0; r < 4; r++) {
                    const int lr = w * 32 + i * 16 + quad * 4 + r;
                    KLP[lr * PS_STRIDE + jf * 16 + fm] = bf16_bits(sacc[i][jf][r]);
                }

        // ---- O += P V (wave reads only its own P rows; in-order LDS per wave) ----
        #pragma unroll
        for (int kc2 = 0; kc2 < 2; kc2++) {
            short8 ap[2];
            #pragma unroll
            for (int i = 0; i < 2; i++)
                ap[i] = *(const short8*)&KLP[(w * 32 + i * 16 + fm) * PS_STRIDE + kc2 * 32 + quad * 8];
            #pragma unroll
            for (int df = 0; df < 8; df++) {
                short8 bv = *(const short8*)&VsT[(df * 16 + fm) * VS_STRIDE + kc2 * 32 + quad * 8];
                #pragma unroll
                for (int i = 0; i < 2; i++)
                    oacc[i][df] = __builtin_amdgcn_mfma_f32_16x16x32_bf16(ap[i], bv, oacc[i][df], 0, 0, 0);
            }
        }
    }

    // ---- epilogue ----
    float linv[2][4];
    #pragma unroll
    for (int i = 0; i < 2; i++)
        #pragma unroll
        for (int r = 0; r < 4; r++) linv[i][r] = 1.0f / l_[i][r];
    #pragma unroll
    for (int i = 0; i < 2; i++)
        #pragma unroll
        for (int df = 0; df < 8; df++)
            #pragma unroll
            for (int r = 0; r < 4; r++) {
                const int row = q0 + w * 32 + i * 16 + quad * 4 + r;
                const int d = df * 16 + fm;
                __hip_bfloat16 ob = __float2bfloat16(oacc[i][df][r] * linv[i][r]);
                AO[base + (size_t)row * rstr + d] = ob;
            }
}

// ======================= launch =======================
extern "C" void kernel_launch(void* const* d_in, const int* in_sizes, int n_in,
                              void* d_out, int out_size, void* d_ws, size_t ws_size,
                              hipStream_t stream) {
    const float* x  = (const float*)d_in[0];
    const float* wq = (const float*)d_in[1];
    const float* wk = (const float*)d_in[2];
    const float* wv = (const float*)d_in[3];
    const float* wo = (const float*)d_in[4];
    const float* q_scale = (const float*)d_in[5];
    const float* k_scale = (const float*)d_in[6];
    float* out = (float*)d_out;

    const size_t T = (size_t)BATCH * SEQ * NH * HD;   // 8388608
    const size_t W = (size_t)EMB * NH * HD;           // 4194304

    float* q = (float*)d_ws;
    float* k = q + T;
    float* v = k + T;
    unsigned short* xh   = (unsigned short*)(v + T);
    unsigned short* xl   = xh + T;
    unsigned short* aob  = xl + T;
    unsigned short* wqTh = aob + T;
    unsigned short* wqTl = wqTh + W;
    unsigned short* wkTh = wqTl + W;
    unsigned short* wkTl = wkTh + W;
    unsigned short* wvT  = wkTl + W;
    unsigned short* woT  = wvT + W;

    const int M = BATCH * SEQ;   // 4096
    const int N = NH * HD;       // 2048
    const int K = EMB;           // 2048

    cast_split_f32<<<(int)(T / 4 + 255) / 256, 256, 0, stream>>>(x, xh, xl, (int)T);
    dim3 tblk(32, 8);
    transpose_cast_split<<<dim3(N / 32, K / 32), tblk, 0, stream>>>(wq, wqTh, wqTl, K, N);
    transpose_cast_split<<<dim3(N / 32, K / 32), tblk, 0, stream>>>(wk, wkTh, wkTl, K, N);
    transpose_cast<<<dim3(N / 32, K / 32), tblk, 0, stream>>>(wv, wvT, K, N);
    transpose_cast<<<dim3(EMB / 32, (NH * HD) / 32), tblk, 0, stream>>>(wo, woT, NH * HD, EMB);

    dim3 ggrid(N / GT, M / GT);
    gemm_bf16_split<<<ggrid, 256, 0, stream>>>(xh, xl, wqTh, wqTl, q, M, N, K);
    gemm_bf16_split<<<ggrid, 256, 0, stream>>>(xh, xl, wkTh, wkTl, k, M, N, K);
    gemm_bf16<<<ggrid, 256, 0, stream>>>(xh, wvT, v, M, N, K);

    rmsnorm_rows<<<M * NH, 128, 0, stream>>>(q, q_scale);
    rmsnorm_rows<<<M * NH, 128, 0, stream>>>(k, k_scale);

    attn_mfma<<<dim3(SEQ / ATQ, BATCH * NH), 256, 0, stream>>>(q, k, v, (__hip_bfloat16*)aob);

    gemm_bf16<<<dim3(EMB / GT, M / GT), 256, 0, stream>>>(aob, woT, out, M, EMB, NH * HD);
}

// Round 4
// 765.571 us; speedup vs baseline: 6.0938x; 1.0464x over previous
//
#include <hip/hip_runtime.h>
#include <hip/hip_bf16.h>
#include <math.h>

#define BATCH 2
#define SEQ   2048
#define EMB   2048
#define NH    16
#define HD    128

typedef __attribute__((ext_vector_type(8))) short short8;
typedef __attribute__((ext_vector_type(4))) float floatx4;

__device__ inline void async_load16(const void* g, void* l) {
    __builtin_amdgcn_global_load_lds(
        (const __attribute__((address_space(1))) unsigned int*)g,
        (__attribute__((address_space(3))) unsigned int*)l, 16, 0, 0);
}

__device__ inline unsigned short bf16_bits(float f) {
    __hip_bfloat16 b = __float2bfloat16(f);
    return *(unsigned short*)&b;
}
__device__ inline void split_bf16(float f, unsigned short& h, unsigned short& l) {
    __hip_bfloat16 hb = __float2bfloat16(f);
    h = *(unsigned short*)&hb;
    float r = f - __bfloat162float(hb);
    __hip_bfloat16 lb = __float2bfloat16(r);
    l = *(unsigned short*)&lb;
}

// ======================= plain bf16 MFMA GEMM (m97 structure) =======================
#define GT 128
#define GK 32

__global__ __launch_bounds__(256) void gemm_bf16(
    const unsigned short* __restrict__ A,
    const unsigned short* __restrict__ Bt,
    float* __restrict__ C, int M, int N, int K)
{
    __shared__ unsigned short As[GT * GK];
    __shared__ unsigned short Bs[GT * GK];

    const int tid  = threadIdx.x;
    const int w    = tid >> 6;
    const int lane = tid & 63;
    const int wr   = w >> 1, wc = w & 1;
    const int row0 = blockIdx.y * GT;
    const int col0 = blockIdx.x * GT;

    floatx4 acc[4][4];
    #pragma unroll
    for (int i = 0; i < 4; i++)
        #pragma unroll
        for (int j = 0; j < 4; j++)
            acc[i][j] = (floatx4){0.f, 0.f, 0.f, 0.f};

    const int srow  = lane >> 2;
    const int skoff = (lane & 3) * 8;
    const int fm = lane & 15;
    const int fk = (lane >> 4) * 8;

    for (int k0 = 0; k0 < K; k0 += GK) {
        #pragma unroll
        for (int t = 0; t < 2; t++) {
            const int c = w * 2 + t;
            async_load16(A  + (size_t)(row0 + c * 16 + srow) * K + k0 + skoff, (char*)As + c * 1024);
            async_load16(Bt + (size_t)(col0 + c * 16 + srow) * K + k0 + skoff, (char*)Bs + c * 1024);
        }
        __syncthreads();

        short8 af[4], bf[4];
        #pragma unroll
        for (int i = 0; i < 4; i++) {
            af[i] = *(const short8*)&As[(wr * 64 + i * 16 + fm) * GK + fk];
            bf[i] = *(const short8*)&Bs[(wc * 64 + i * 16 + fm) * GK + fk];
        }
        #pragma unroll
        for (int i = 0; i < 4; i++)
            #pragma unroll
            for (int j = 0; j < 4; j++)
                acc[i][j] = __builtin_amdgcn_mfma_f32_16x16x32_bf16(af[i], bf[j], acc[i][j], 0, 0, 0);
        __syncthreads();
    }

    const int quad = lane >> 4;
    #pragma unroll
    for (int i = 0; i < 4; i++)
        #pragma unroll
        for (int j = 0; j < 4; j++) {
            const size_t base = (size_t)(row0 + wr * 64 + i * 16 + quad * 4) * N
                              + col0 + wc * 64 + j * 16 + fm;
            #pragma unroll
            for (int r = 0; r < 4; r++)
                C[base + (size_t)r * N] = acc[i][j][r];
        }
}

// ======================= split (hi/lo) bf16 MFMA GEMM =======================
__global__ __launch_bounds__(256) void gemm_bf16_split(
    const unsigned short* __restrict__ Ah, const unsigned short* __restrict__ Al,
    const unsigned short* __restrict__ Bh, const unsigned short* __restrict__ Bl,
    float* __restrict__ C, int M, int N, int K)
{
    __shared__ unsigned short AsH[GT * GK], AsL[GT * GK];
    __shared__ unsigned short BsH[GT * GK], BsL[GT * GK];

    const int tid  = threadIdx.x;
    const int w    = tid >> 6;
    const int lane = tid & 63;
    const int wr   = w >> 1, wc = w & 1;
    const int row0 = blockIdx.y * GT;
    const int col0 = blockIdx.x * GT;

    floatx4 acc[4][4];
    #pragma unroll
    for (int i = 0; i < 4; i++)
        #pragma unroll
        for (int j = 0; j < 4; j++)
            acc[i][j] = (floatx4){0.f, 0.f, 0.f, 0.f};

    const int srow  = lane >> 2;
    const int skoff = (lane & 3) * 8;
    const int fm = lane & 15;
    const int fk = (lane >> 4) * 8;

    for (int k0 = 0; k0 < K; k0 += GK) {
        #pragma unroll
        for (int t = 0; t < 2; t++) {
            const int c = w * 2 + t;
            const size_t ao = (size_t)(row0 + c * 16 + srow) * K + k0 + skoff;
            const size_t bo = (size_t)(col0 + c * 16 + srow) * K + k0 + skoff;
            async_load16(Ah + ao, (char*)AsH + c * 1024);
            async_load16(Al + ao, (char*)AsL + c * 1024);
            async_load16(Bh + bo, (char*)BsH + c * 1024);
            async_load16(Bl + bo, (char*)BsL + c * 1024);
        }
        __syncthreads();

        short8 afh[4], afl[4], bfh[4], bfl[4];
        #pragma unroll
        for (int i = 0; i < 4; i++) {
            const int arow = (wr * 64 + i * 16 + fm) * GK + fk;
            const int brow = (wc * 64 + i * 16 + fm) * GK + fk;
            afh[i] = *(const short8*)&AsH[arow];
            afl[i] = *(const short8*)&AsL[arow];
            bfh[i] = *(const short8*)&BsH[brow];
            bfl[i] = *(const short8*)&BsL[brow];
        }
        #pragma unroll
        for (int i = 0; i < 4; i++)
            #pragma unroll
            for (int j = 0; j < 4; j++) {
                acc[i][j] = __builtin_amdgcn_mfma_f32_16x16x32_bf16(afh[i], bfh[j], acc[i][j], 0, 0, 0);
                acc[i][j] = __builtin_amdgcn_mfma_f32_16x16x32_bf16(afh[i], bfl[j], acc[i][j], 0, 0, 0);
                acc[i][j] = __builtin_amdgcn_mfma_f32_16x16x32_bf16(afl[i], bfh[j], acc[i][j], 0, 0, 0);
            }
        __syncthreads();
    }

    const int quad = lane >> 4;
    #pragma unroll
    for (int i = 0; i < 4; i++)
        #pragma unroll
        for (int j = 0; j < 4; j++) {
            const size_t base = (size_t)(row0 + wr * 64 + i * 16 + quad * 4) * N
                              + col0 + wc * 64 + j * 16 + fm;
            #pragma unroll
            for (int r = 0; r < 4; r++)
                C[base + (size_t)r * N] = acc[i][j][r];
        }
}

// ======================= casts / weight prep =======================
__global__ __launch_bounds__(256) void cast_split_f32(
    const float* __restrict__ in, unsigned short* __restrict__ hi,
    unsigned short* __restrict__ lo, int n)
{
    int i = (blockIdx.x * 256 + threadIdx.x) * 4;
    if (i >= n) return;
    float4 v = *(const float4*)&in[i];
    ushort4 h, l;
    split_bf16(v.x, h.x, l.x);
    split_bf16(v.y, h.y, l.y);
    split_bf16(v.z, h.z, l.z);
    split_bf16(v.w, h.w, l.w);
    *(ushort4*)&hi[i] = h;
    *(ushort4*)&lo[i] = l;
}

__global__ __launch_bounds__(256) void transpose_cast(
    const float* __restrict__ W, unsigned short* __restrict__ Wt, int K, int N)
{
    __shared__ float tile[32][33];
    const int k0 = blockIdx.y * 32, n0 = blockIdx.x * 32;
    const int tx = threadIdx.x, ty = threadIdx.y;
    #pragma unroll
    for (int i = 0; i < 4; i++)
        tile[ty + i * 8][tx] = W[(size_t)(k0 + ty + i * 8) * N + n0 + tx];
    __syncthreads();
    #pragma unroll
    for (int i = 0; i < 4; i++)
        Wt[(size_t)(n0 + ty + i * 8) * K + k0 + tx] = bf16_bits(tile[tx][ty + i * 8]);
}

__global__ __launch_bounds__(256) void transpose_cast_split(
    const float* __restrict__ W, unsigned short* __restrict__ WtH,
    unsigned short* __restrict__ WtL, int K, int N)
{
    __shared__ float tile[32][33];
    const int k0 = blockIdx.y * 32, n0 = blockIdx.x * 32;
    const int tx = threadIdx.x, ty = threadIdx.y;
    #pragma unroll
    for (int i = 0; i < 4; i++)
        tile[ty + i * 8][tx] = W[(size_t)(k0 + ty + i * 8) * N + n0 + tx];
    __syncthreads();
    #pragma unroll
    for (int i = 0; i < 4; i++) {
        unsigned short h, l;
        split_bf16(tile[tx][ty + i * 8], h, l);
        size_t idx = (size_t)(n0 + ty + i * 8) * K + k0 + tx;
        WtH[idx] = h;
        WtL[idx] = l;
    }
}

// ======================= prep_qk: rmsnorm + split + head-major relayout =======================
// in: fp32 [b,s,h,d]; out: hi/lo bf16 [b,h,s,d]. swz!=0 -> 16B-chunk XOR swizzle (for K).
// grid: B*SEQ*NH/2 blocks of 256 (2 rows per block).
__global__ __launch_bounds__(256) void prep_qk(
    const float* __restrict__ in, const float* __restrict__ scale,
    unsigned short* __restrict__ hi, unsigned short* __restrict__ lo, int swz)
{
    __shared__ float ws4[4];
    const int r = blockIdx.x * 2 + (threadIdx.x >> 7);
    const int d = threadIdx.x & 127;
    const int b = r >> 15;            // / (SEQ*NH)
    const int s = (r >> 4) & 2047;    // / NH % SEQ
    const int h = r & 15;
    const float v = in[(size_t)r * 128 + d];
    float ss = v * v;
    #pragma unroll
    for (int off = 1; off < 64; off <<= 1) ss += __shfl_xor(ss, off, 64);
    if ((threadIdx.x & 63) == 0) ws4[threadIdx.x >> 6] = ss;
    __syncthreads();
    const int g = (threadIdx.x >> 7) << 1;
    const float inv = rsqrtf((ws4[g] + ws4[g + 1]) * (1.0f / HD) + 1e-6f);
    const float val = v * inv * scale[d];
    unsigned short hb, lb;
    split_bf16(val, hb, lb);
    const int dd = swz ? (((((d >> 3) ^ (s & 15))) << 3) | (d & 7)) : d;
    const size_t o = ((size_t)(b * NH + h) * SEQ + s) * 128 + dd;
    hi[o] = hb;
    lo[o] = lb;
}

// ======================= prep_v: v[b,s,h,d] fp32 -> Vt[(b,h,kt)][d][key'] bf16 =======================
// tile-blocked transpose; key-chunk swizzle ^(d&7). grid (32, B*NH), block 256.
__global__ __launch_bounds__(256) void prep_v(
    const float* __restrict__ v, unsigned short* __restrict__ Vt)
{
    __shared__ unsigned short T[128][72];   // [d][key], rows 144 B (16B-aligned)
    const int bh = blockIdx.y, ktile = blockIdx.x;
    const int b = bh >> 4, h = bh & 15;
    const int key = threadIdx.x >> 2, dg = threadIdx.x & 3;
    const size_t vrow = ((size_t)(b * SEQ + ktile * 64 + key) * NH + h) * 128;
    #pragma unroll
    for (int i2 = 0; i2 < 8; i2++) {
        const int d0 = dg * 4 + i2 * 16;
        float4 x = *(const float4*)&v[vrow + d0];
        T[d0 + 0][key] = bf16_bits(x.x);
        T[d0 + 1][key] = bf16_bits(x.y);
        T[d0 + 2][key] = bf16_bits(x.z);
        T[d0 + 3][key] = bf16_bits(x.w);
    }
    __syncthreads();
    const int d = threadIdx.x >> 1, half = threadIdx.x & 1;
    const size_t obase = ((size_t)bh * 32 + ktile) * 8192 + (size_t)d * 64;
    #pragma unroll
    for (int cc = 0; cc < 4; cc++) {
        const int cs = half * 4 + cc;
        const int kb = (cs ^ (d & 7)) << 3;
        short8 val = *(const short8*)&T[d][kb];
        *(short8*)&Vt[obase + cs * 8] = val;
    }
}

// ======================= MFMA flash attention v2 (async staging, pre-split K) =======================
// grid (SEQ/128, BATCH*NH), 256 threads = 4 waves; wave w owns q-rows w*32..+31.
#define ATQ 128
#define ATK 64

__global__ __launch_bounds__(256, 2) void attn2(
    const unsigned short* __restrict__ Qh, const unsigned short* __restrict__ Ql,
    const unsigned short* __restrict__ Kh, const unsigned short* __restrict__ Kl,
    const unsigned short* __restrict__ Vt, __hip_bfloat16* __restrict__ AO)
{
    __shared__ unsigned short KsH[ATK * 128];   // 16 KB  [key][d']  (chunk ^= key&15)
    __shared__ unsigned short KLP[ATK * 128];   // 16 KB  KsL, then P[128][64'] (chunk ^= row&7)
    __shared__ unsigned short Vts[HD * 64];     // 16 KB  [d][key'] (chunk ^= d&7)

    const int tid  = threadIdx.x;
    const int w    = tid >> 6;
    const int lane = tid & 63;
    const int quad = lane >> 4;
    const int fm   = lane & 15;
    const int bh = blockIdx.y;
    const int b = bh >> 4, h = bh & 15;
    const int q0 = blockIdx.x * ATQ;

    const size_t hbase = (size_t)(b * NH + h) * SEQ;   // row units in [b,h,s,d]

    // ---- Q fragments (pre-split bf16, plain layout) ----
    short8 qh[2][4], ql[2][4];
    #pragma unroll
    for (int i = 0; i < 2; i++) {
        const size_t row = hbase + q0 + w * 32 + i * 16 + fm;
        #pragma unroll
        for (int kc = 0; kc < 4; kc++) {
            const size_t off = row * 128 + kc * 32 + quad * 8;
            qh[i][kc] = *(const short8*)&Qh[off];
            ql[i][kc] = *(const short8*)&Ql[off];
        }
    }

    floatx4 oacc[2][8];
    #pragma unroll
    for (int i = 0; i < 2; i++)
        #pragma unroll
        for (int df = 0; df < 8; df++)
            oacc[i][df] = (floatx4){0.f, 0.f, 0.f, 0.f};
    float m_[2][4], l_[2][4];
    #pragma unroll
    for (int i = 0; i < 2; i++)
        #pragma unroll
        for (int r = 0; r < 4; r++) { m_[i][r] = -1e30f; l_[i][r] = 0.f; }

    for (int ktile = 0; ktile < SEQ / ATK; ktile++) {
        __syncthreads();   // B1: prev PV (P, Vts) and S (KsH) reads complete

        // ---- async staging: 16 chunks of 1 KB per buffer, 4 per wave ----
        const unsigned short* gkh = Kh + (hbase + ktile * ATK) * 128;
        const unsigned short* gkl = Kl + (hbase + ktile * ATK) * 128;
        const unsigned short* gvt = Vt + ((size_t)bh * 32 + ktile) * 8192;
        #pragma unroll
        for (int c = 0; c < 4; c++) {
            const int ch = w * 4 + c;
            const size_t go = (size_t)ch * 512 + lane * 8;
            async_load16(gkh + go, (char*)KsH + ch * 1024);
            async_load16(gkl + go, (char*)KLP + ch * 1024);
            async_load16(gvt + go, (char*)Vts + ch * 1024);
        }
        __syncthreads();   // B2: staging visible

        // ---- S = Q K^T (3-term) ----
        floatx4 sacc[2][4];
        #pragma unroll
        for (int i = 0; i < 2; i++)
            #pragma unroll
            for (int jf = 0; jf < 4; jf++)
                sacc[i][jf] = (floatx4){0.f, 0.f, 0.f, 0.f};
        #pragma unroll
        for (int kc = 0; kc < 4; kc++)
            #pragma unroll
            for (int jf = 0; jf < 4; jf++) {
                const int koff = (jf * 16 + fm) * 128 + (((kc * 4 + quad) ^ fm) << 3);
                short8 kh8 = *(const short8*)&KsH[koff];
                short8 kl8 = *(const short8*)&KLP[koff];
                #pragma unroll
                for (int i = 0; i < 2; i++) {
                    sacc[i][jf] = __builtin_amdgcn_mfma_f32_16x16x32_bf16(qh[i][kc], kh8, sacc[i][jf], 0, 0, 0);
                    sacc[i][jf] = __builtin_amdgcn_mfma_f32_16x16x32_bf16(qh[i][kc], kl8, sacc[i][jf], 0, 0, 0);
                    sacc[i][jf] = __builtin_amdgcn_mfma_f32_16x16x32_bf16(ql[i][kc], kh8, sacc[i][jf], 0, 0, 0);
                }
            }

        // ---- online softmax (registers) ----
        float alpha_[2][4];
        #pragma unroll
        for (int i = 0; i < 2; i++)
            #pragma unroll
            for (int r = 0; r < 4; r++) {
                float mx = fmaxf(fmaxf(sacc[i][0][r], sacc[i][1][r]),
                                 fmaxf(sacc[i][2][r], sacc[i][3][r]));
                mx = fmaxf(mx, __shfl_xor(mx, 1));
                mx = fmaxf(mx, __shfl_xor(mx, 2));
                mx = fmaxf(mx, __shfl_xor(mx, 4));
                mx = fmaxf(mx, __shfl_xor(mx, 8));
                const float mold = m_[i][r];
                const float mnew = fmaxf(mold, mx);
                const float al = __expf(mold - mnew);
                m_[i][r] = mnew;
                alpha_[i][r] = al;
                float rs = 0.f;
                #pragma unroll
                for (int jf = 0; jf < 4; jf++) {
                    float p = __expf(sacc[i][jf][r] - mnew);
                    sacc[i][jf][r] = p;
                    rs += p;
                }
                rs += __shfl_xor(rs, 1);
                rs += __shfl_xor(rs, 2);
                rs += __shfl_xor(rs, 4);
                rs += __shfl_xor(rs, 8);
                l_[i][r] = l_[i][r] * al + rs;
            }
        #pragma unroll
        for (int i = 0; i < 2; i++)
            #pragma unroll
            for (int df = 0; df < 8; df++)
                #pragma unroll
                for (int r = 0; r < 4; r++)
                    oacc[i][df][r] *= alpha_[i][r];

        __syncthreads();   // B3: all waves done reading KsL before P overwrite

        // ---- P -> bf16 into KLP (swizzled; own rows only) ----
        #pragma unroll
        for (int i = 0; i < 2; i++)
            #pragma unroll
            for (int jf = 0; jf < 4; jf++)
                #pragma unroll
                for (int r = 0; r < 4; r++) {
                    const int row = w * 32 + i * 16 + quad * 4 + r;
                    const int chunk = jf * 2 + (fm >> 3);
                    const int colp = ((chunk ^ (row & 7)) << 3) | (fm & 7);
                    KLP[row * 64 + colp] = bf16_bits(sacc[i][jf][r]);
                }

        // ---- O += P V (own P rows; wave-local LDS ordering, no barrier) ----
        #pragma unroll
        for (int kc2 = 0; kc2 < 2; kc2++) {
            short8 ap[2];
            #pragma unroll
            for (int i = 0; i < 2; i++) {
                const int row = w * 32 + i * 16 + fm;
                ap[i] = *(const short8*)&KLP[row * 64 + (((kc2 * 4 + quad) ^ (row & 7)) << 3)];
            }
            #pragma unroll
            for (int df = 0; df < 8; df++) {
                const int d = df * 16 + fm;
                short8 bv = *(const short8*)&Vts[d * 64 + (((kc2 * 4 + quad) ^ (d & 7)) << 3)];
                #pragma unroll
                for (int i = 0; i < 2; i++)
                    oacc[i][df] = __builtin_amdgcn_mfma_f32_16x16x32_bf16(ap[i], bv, oacc[i][df], 0, 0, 0);
            }
        }
    }

    // ---- epilogue: AO bf16 [b,s,h,d] ----
    const size_t obase = ((size_t)b * SEQ * NH + h) * HD;
    const size_t rstr = (size_t)NH * HD;
    float linv[2][4];
    #pragma unroll
    for (int i = 0; i < 2; i++)
        #pragma unroll
        for (int r = 0; r < 4; r++) linv[i][r] = 1.0f / l_[i][r];
    #pragma unroll
    for (int i = 0; i < 2; i++)
        #pragma unroll
        for (int df = 0; df < 8; df++)
            #pragma unroll
            for (int r = 0; r < 4; r++) {
                const int row = q0 + w * 32 + i * 16 + quad * 4 + r;
                const int d = df * 16 + fm;
                AO[obase + (size_t)row * rstr + d] = __float2bfloat16(oacc[i][df][r] * linv[i][r]);
            }
}

// ======================= launch =======================
extern "C" void kernel_launch(void* const* d_in, const int* in_sizes, int n_in,
                              void* d_out, int out_size, void* d_ws, size_t ws_size,
                              hipStream_t stream) {
    const float* x  = (const float*)d_in[0];
    const float* wq = (const float*)d_in[1];
    const float* wk = (const float*)d_in[2];
    const float* wv = (const float*)d_in[3];
    const float* wo = (const float*)d_in[4];
    const float* q_scale = (const float*)d_in[5];
    const float* k_scale = (const float*)d_in[6];
    float* out = (float*)d_out;

    const size_t T = (size_t)BATCH * SEQ * NH * HD;   // 8388608
    const size_t W = (size_t)EMB * NH * HD;           // 4194304

    float* q = (float*)d_ws;                          // fp32 [b,s,h,d]
    float* k = q + T;
    float* v = k + T;
    unsigned short* xh   = (unsigned short*)(v + T);  // also reused as Qh after GEMMs
    unsigned short* xl   = xh + T;                    // also reused as Ql
    unsigned short* aob  = xl + T;
    unsigned short* Kh   = aob + T;
    unsigned short* Kl   = Kh + T;
    unsigned short* Vtb  = Kl + T;
    unsigned short* wqTh = Vtb + T;
    unsigned short* wqTl = wqTh + W;
    unsigned short* wkTh = wqTl + W;
    unsigned short* wkTl = wkTh + W;
    unsigned short* wvT  = wkTl + W;
    unsigned short* woT  = wvT + W;

    const int M = BATCH * SEQ;   // 4096
    const int N = NH * HD;       // 2048
    const int K = EMB;           // 2048

    cast_split_f32<<<(int)(T / 4 + 255) / 256, 256, 0, stream>>>(x, xh, xl, (int)T);
    dim3 tblk(32, 8);
    transpose_cast_split<<<dim3(N / 32, K / 32), tblk, 0, stream>>>(wq, wqTh, wqTl, K, N);
    transpose_cast_split<<<dim3(N / 32, K / 32), tblk, 0, stream>>>(wk, wkTh, wkTl, K, N);
    transpose_cast<<<dim3(N / 32, K / 32), tblk, 0, stream>>>(wv, wvT, K, N);
    transpose_cast<<<dim3(EMB / 32, (NH * HD) / 32), tblk, 0, stream>>>(wo, woT, NH * HD, EMB);

    dim3 ggrid(N / GT, M / GT);
    gemm_bf16_split<<<ggrid, 256, 0, stream>>>(xh, xl, wqTh, wqTl, q, M, N, K);
    gemm_bf16_split<<<ggrid, 256, 0, stream>>>(xh, xl, wkTh, wkTl, k, M, N, K);
    gemm_bf16<<<ggrid, 256, 0, stream>>>(xh, wvT, v, M, N, K);

    // prep: rmsnorm+split+relayout (x staging buffers now free -> reuse as Qh/Ql)
    unsigned short* Qh = xh;
    unsigned short* Ql = xl;
    prep_qk<<<(int)(T / 128 / 2), 256, 0, stream>>>(q, q_scale, Qh, Ql, 0);
    prep_qk<<<(int)(T / 128 / 2), 256, 0, stream>>>(k, k_scale, Kh, Kl, 1);
    prep_v<<<dim3(SEQ / ATK, BATCH * NH), 256, 0, stream>>>(v, Vtb);

    attn2<<<dim3(SEQ / ATQ, BATCH * NH), 256, 0, stream>>>(Qh, Ql, Kh, Kl, Vtb, (__hip_bfloat16*)aob);

    gemm_bf16<<<dim3(EMB / GT, M / GT), 256, 0, stream>>>(aob, woT, out, M, EMB, NH * HD);
}